// Round 1
// baseline (506.726 us; speedup 1.0000x reference)
//
#include <hip/hip_runtime.h>
#include <hip/hip_bf16.h>

#define N_CTX 4096
#define DM    2048

typedef __attribute__((ext_vector_type(8))) short short8;
typedef __attribute__((ext_vector_type(4))) float f32x4;
typedef unsigned short ushort_t;

__device__ __forceinline__ ushort_t f2bf(float x) {
    __hip_bfloat16 h = __float2bfloat16(x);
    return __builtin_bit_cast(ushort_t, h);
}
__device__ __forceinline__ float bf2f(ushort_t u) {
    return __bfloat162float(__builtin_bit_cast(__hip_bfloat16, u));
}

__device__ __forceinline__ void gload16(const void* g, void* l) {
    __builtin_amdgcn_global_load_lds((const __attribute__((address_space(1))) void*)g,
                                     (__attribute__((address_space(3))) void*)l,
                                     16, 0, 0);
}

// ---------------- cast kernels ----------------

__global__ __launch_bounds__(256) void split_cast_kernel(
    const float* __restrict__ in, ushort_t* __restrict__ hi, ushort_t* __restrict__ lo, int n4)
{
    int idx = blockIdx.x * 256 + threadIdx.x;
    if (idx >= n4) return;
    float4 v = reinterpret_cast<const float4*>(in)[idx];
    float vv[4] = {v.x, v.y, v.z, v.w};
    ushort_t h[4], l[4];
#pragma unroll
    for (int j = 0; j < 4; ++j) {
        h[j] = f2bf(vv[j]);
        l[j] = f2bf(vv[j] - bf2f(h[j]));
    }
    reinterpret_cast<ushort4*>(hi)[idx] = *reinterpret_cast<ushort4*>(h);
    reinterpret_cast<ushort4*>(lo)[idx] = *reinterpret_cast<ushort4*>(l);
}

// in: f32 [R][C]; out: bf16 [C][R] (transposed). Optional lo part.
template <bool SPLIT>
__global__ __launch_bounds__(256) void transpose_cast_kernel(
    const float* __restrict__ in, ushort_t* __restrict__ hi, ushort_t* __restrict__ lo,
    int R, int C)
{
    __shared__ float tile[32][33];
    int bc = blockIdx.x * 32;   // col base in input
    int br = blockIdx.y * 32;   // row base in input
    int tx = threadIdx.x, ty = threadIdx.y;   // (32, 8)
#pragma unroll
    for (int r = ty; r < 32; r += 8)
        tile[r][tx] = in[(size_t)(br + r) * C + bc + tx];
    __syncthreads();
#pragma unroll
    for (int c = ty; c < 32; c += 8) {
        float v = tile[tx][c];
        size_t o = (size_t)(bc + c) * R + br + tx;
        ushort_t h = f2bf(v);
        hi[o] = h;
        if (SPLIT) lo[o] = f2bf(v - bf2f(h));
    }
}

// ---------------- GEMM: C[M][N] = sum_p A_p (128-row tiles) @ B_p^T ----------------
// A_p: [M][K] bf16 row-major, B_p: [N][K] bf16 row-major (i.e. B transposed).
// OM: 0 = f32 out, 1 = bf16 out, 2 = split bf16 (hi+lo) out.
// CAUSAL: skip blocks entirely above the diagonal (output col > row).

template <int NP, int OM, bool CAUSAL>
__global__ __launch_bounds__(256, 2) void gemm_bt_kernel(
    const ushort_t* __restrict__ A0, const ushort_t* __restrict__ B0,
    const ushort_t* __restrict__ A1, const ushort_t* __restrict__ B1,
    const ushort_t* __restrict__ A2, const ushort_t* __restrict__ B2,
    int K, int ldc,
    float* __restrict__ Cf, ushort_t* __restrict__ Ch, ushort_t* __restrict__ Cl)
{
    const int bx = blockIdx.x;   // N tile
    const int by = blockIdx.y;   // M tile
    if (CAUSAL && bx * 128 > by * 128 + 127) return;

    __shared__ ushort_t Asm[128 * 64];   // 16 KB, [row][64 k] with chunk-XOR swizzle
    __shared__ ushort_t Bsm[128 * 64];   // 16 KB

    const int t = threadIdx.x;
    const int l = t & 63;
    const int w = t >> 6;
    const int wr = w >> 1;   // wave row (0..1) -> 64 rows of M
    const int wc = w & 1;    // wave col (0..1) -> 64 cols of N

    f32x4 zero = {0.f, 0.f, 0.f, 0.f};
    f32x4 acc[4][4];
#pragma unroll
    for (int m = 0; m < 4; ++m)
#pragma unroll
        for (int n = 0; n < 4; ++n) acc[m][n] = zero;

    const size_t arow0 = (size_t)by * 128;
    const size_t brow0 = (size_t)bx * 128;

    const ushort_t* Aps[3] = {A0, A1, A2};
    const ushort_t* Bps[3] = {B0, B1, B2};

#pragma unroll
    for (int pt = 0; pt < NP; ++pt) {
        const ushort_t* Ap = Aps[pt];
        const ushort_t* Bp = Bps[pt];
        for (int kt = 0; kt < K; kt += 64) {
            __syncthreads();   // previous iteration's reads done before overwrite
            // stage A and B tiles: 128 rows x 64 k x bf16 = 16KB each.
            // flat 16B-chunk index f: row = f>>3, lds chunk col = f&7.
            // inverse-swizzle the SOURCE chunk so a swizzled read sees linear data.
#pragma unroll
            for (int i = 0; i < 4; ++i) {
                int f = i * 256 + t;
                int r = f >> 3;
                int cch = (f & 7) ^ (r & 7);
                const ushort_t* ga = Ap + (arow0 + r) * (size_t)K + kt + cch * 8;
                gload16(ga, (char*)Asm + (i * 256 + w * 64) * 16);
                const ushort_t* gb = Bp + (brow0 + r) * (size_t)K + kt + cch * 8;
                gload16(gb, (char*)Bsm + (i * 256 + w * 64) * 16);
            }
            __syncthreads();   // compiler drains vmcnt before s_barrier

#pragma unroll
            for (int kk = 0; kk < 2; ++kk) {
                short8 af[4], bfr[4];
#pragma unroll
                for (int m = 0; m < 4; ++m) {
                    int row = wr * 64 + m * 16 + (l & 15);
                    int gby = kk * 64 + (l >> 4) * 16;
                    af[m] = *(const short8*)((const char*)Asm + row * 128 +
                                             (gby ^ ((row & 7) * 16)));
                }
#pragma unroll
                for (int n = 0; n < 4; ++n) {
                    int row = wc * 64 + n * 16 + (l & 15);
                    int gby = kk * 64 + (l >> 4) * 16;
                    bfr[n] = *(const short8*)((const char*)Bsm + row * 128 +
                                              (gby ^ ((row & 7) * 16)));
                }
#pragma unroll
                for (int m = 0; m < 4; ++m)
#pragma unroll
                    for (int n = 0; n < 4; ++n)
                        acc[m][n] = __builtin_amdgcn_mfma_f32_16x16x32_bf16(
                            af[m], bfr[n], acc[m][n], 0, 0, 0);
            }
        }
    }

    // epilogue: C/D layout col = lane&15, row = (lane>>4)*4 + reg
    const int r0 = by * 128 + wr * 64 + ((l >> 4) << 2);
    const int c0 = bx * 128 + wc * 64 + (l & 15);
#pragma unroll
    for (int m = 0; m < 4; ++m) {
#pragma unroll
        for (int n = 0; n < 4; ++n) {
#pragma unroll
            for (int j = 0; j < 4; ++j) {
                size_t o = (size_t)(r0 + m * 16 + j) * ldc + (c0 + n * 16);
                float v = acc[m][n][j];
                if (OM == 0) {
                    Cf[o] = v;
                } else if (OM == 1) {
                    Ch[o] = f2bf(v);
                } else {
                    ushort_t h = f2bf(v);
                    Ch[o] = h;
                    Cl[o] = f2bf(v - bf2f(h));
                }
            }
        }
    }
}

// ---------------- causal row softmax ----------------

__device__ __forceinline__ float waveMax(float v) {
#pragma unroll
    for (int o = 32; o > 0; o >>= 1) v = fmaxf(v, __shfl_xor(v, o, 64));
    return v;
}
__device__ __forceinline__ float waveSum(float v) {
#pragma unroll
    for (int o = 32; o > 0; o >>= 1) v += __shfl_xor(v, o, 64);
    return v;
}

__global__ __launch_bounds__(256) void softmax_kernel(
    const float* __restrict__ S, ushort_t* __restrict__ A)
{
    const int i = blockIdx.x;
    __shared__ float row[N_CTX];
    __shared__ float red[8];
    const int t = threadIdx.x;
    const int len = i + 1;   // causal: only j <= i participate
    const float* Srow = S + (size_t)i * N_CTX;

    float m = -3.4e38f;
    for (int j = t; j < len; j += 256) {
        float v = Srow[j];
        row[j] = v;
        m = fmaxf(m, v);
    }
    m = waveMax(m);
    if ((t & 63) == 0) red[t >> 6] = m;
    __syncthreads();
    m = fmaxf(fmaxf(red[0], red[1]), fmaxf(red[2], red[3]));

    float s = 0.f;
    for (int j = t; j < len; j += 256) {
        float e = __expf(row[j] - m);
        row[j] = e;
        s += e;
    }
    s = waveSum(s);
    __syncthreads();
    if ((t & 63) == 0) red[t >> 6] = s;
    __syncthreads();
    float inv = 1.f / (red[0] + red[1] + red[2] + red[3]);

    ushort_t* Arow = A + (size_t)i * N_CTX;
    for (int j = t; j < N_CTX; j += 256)
        Arow[j] = (j < len) ? f2bf(row[j] * inv) : (ushort_t)0;
}

// ---------------- launcher ----------------

extern "C" void kernel_launch(void* const* d_in, const int* in_sizes, int n_in,
                              void* d_out, int out_size, void* d_ws, size_t ws_size,
                              hipStream_t stream)
{
    const float* E  = (const float*)d_in[0];
    const float* qk = (const float*)d_in[1];
    const float* ov = (const float*)d_in[2];
    float* out = (float*)d_out;

    char* ws = (char*)d_ws;
    size_t off = 0;
    auto take = [&](size_t bytes) -> char* {
        char* p = ws + off;
        off += (bytes + 255) & ~(size_t)255;
        return p;
    };

    ushort_t* Ehi   = (ushort_t*)take((size_t)N_CTX * DM * 2);
    ushort_t* Elo   = (ushort_t*)take((size_t)N_CTX * DM * 2);
    ushort_t* Et    = (ushort_t*)take((size_t)N_CTX * DM * 2);   // E^T [DM][N_CTX]
    ushort_t* QKthi = (ushort_t*)take((size_t)DM * DM * 2);      // qk^T
    ushort_t* QKtlo = (ushort_t*)take((size_t)DM * DM * 2);
    ushort_t* OVt   = (ushort_t*)take((size_t)DM * DM * 2);      // ov^T
    ushort_t* Qhi   = (ushort_t*)take((size_t)N_CTX * DM * 2);
    ushort_t* Qlo   = (ushort_t*)take((size_t)N_CTX * DM * 2);
    float*    S     = (float*)take((size_t)N_CTX * N_CTX * 4);
    ushort_t* Attn  = (ushort_t*)take((size_t)N_CTX * N_CTX * 2);
    ushort_t* Hbf   = (ushort_t*)take((size_t)N_CTX * DM * 2);
    (void)ws_size; (void)in_sizes; (void)n_in; (void)out_size;

    // 1. casts
    split_cast_kernel<<<dim3((N_CTX * DM / 4) / 256), 256, 0, stream>>>(E, Ehi, Elo, N_CTX * DM / 4);
    transpose_cast_kernel<true ><<<dim3(DM / 32, DM / 32),    dim3(32, 8), 0, stream>>>(qk, QKthi, QKtlo, DM, DM);
    transpose_cast_kernel<false><<<dim3(DM / 32, DM / 32),    dim3(32, 8), 0, stream>>>(ov, OVt, nullptr, DM, DM);
    transpose_cast_kernel<false><<<dim3(DM / 32, N_CTX / 32), dim3(32, 8), 0, stream>>>(E, Et, nullptr, N_CTX, DM);

    // 2. Q = E @ qk  (split precision in, split bf16 out)
    gemm_bt_kernel<3, 2, false><<<dim3(DM / 128, N_CTX / 128), 256, 0, stream>>>(
        Ehi, QKthi, Ehi, QKtlo, Elo, QKthi, DM, DM, nullptr, Qhi, Qlo);

    // 3. S = Q @ E^T  (split precision, causal block skip, f32 out)
    gemm_bt_kernel<3, 0, true><<<dim3(N_CTX / 128, N_CTX / 128), 256, 0, stream>>>(
        Qhi, Ehi, Qhi, Elo, Qlo, Ehi, DM, N_CTX, S, nullptr, nullptr);

    // 4. attn = causal softmax(S), bf16
    softmax_kernel<<<N_CTX, 256, 0, stream>>>(S, Attn);

    // 5. H = attn @ E  (bf16 out)
    gemm_bt_kernel<1, 1, false><<<dim3(DM / 128, N_CTX / 128), 256, 0, stream>>>(
        Attn, Et, nullptr, nullptr, nullptr, nullptr, N_CTX, DM, nullptr, Hbf, nullptr);

    // 6. out = H @ ov  (f32 out)
    gemm_bt_kernel<1, 0, false><<<dim3(DM / 128, N_CTX / 128), 256, 0, stream>>>(
        Hbf, OVt, nullptr, nullptr, nullptr, nullptr, DM, DM, out, nullptr, nullptr);
}